// Round 1
// baseline (162.926 us; speedup 1.0000x reference)
//
#include <hip/hip_runtime.h>
#include <math.h>

// NEAT network forward: B=1024, layers 8x1024 + 256, DEG=64 gathers/neuron.
// Strategy: 4 batch elements per block; entire activation history (8960
// neurons x 4 batches, f32) lives in LDS (143,360 B). 9 layers computed
// in one kernel with __syncthreads() between layers.
// Wave layout: lane = nsub*16 + esub; 4 neurons/wave, 16 lanes/neuron,
// 4 edges/lane via int4/float4 loads (coalesced), float4 LDS gather pulls
// all 4 batch values per source in one ds_read_b128.

#define N_IN    512
#define NLAYER  9
#define DEG     64
#define BATCH   1024
#define BPB     4
#define THREADS 1024
#define TOTAL_N 8960   // 512 + 8*1024 + 256
#define N_OUT   256

__global__ __launch_bounds__(THREADS, 4)
void neat_fwd(const float* __restrict__ in,
              const float* __restrict__ wts,
              const int*   __restrict__ sidx,
              float*       __restrict__ out)
{
    __shared__ float act[TOTAL_N * BPB];   // [neuron][batch-sub], 143,360 B

    const int tid   = threadIdx.x;
    const int bbase = blockIdx.x * BPB;

    // ---- stage inputs: rows bbase..bbase+3 are 2048 contiguous floats ----
    {
        const float* src = in + bbase * N_IN;
        for (int t = tid; t < BPB * N_IN; t += THREADS) {
            int j = t >> 9;          // batch sub 0..3
            int i = t & (N_IN - 1);  // input neuron 0..511
            act[i * BPB + j] = src[t];
        }
    }
    __syncthreads();

    const int wave = tid >> 6;   // 0..15
    const int lane = tid & 63;
    const int nsub = lane >> 4;  // 0..3  (neuron within wave-group)
    const int esub = lane & 15;  // 0..15 (edge-quad within neuron)

    int off = 0;      // edge-array offset
    int nb  = N_IN;   // neurons produced so far
    #pragma unroll 1
    for (int layer = 0; layer < NLAYER; ++layer) {
        const int n = (layer < NLAYER - 1) ? 1024 : 256;
        for (int n0 = wave * 4; n0 < n; n0 += 64) {
            const int neuron = n0 + nsub;
            const int ebase  = off + (neuron << 6) + (esub << 2);
            const int4   s4 = *reinterpret_cast<const int4*>(sidx + ebase);
            const float4 w4 = *reinterpret_cast<const float4*>(wts + ebase);

            const float4 a0 = *reinterpret_cast<const float4*>(&act[s4.x << 2]);
            const float4 a1 = *reinterpret_cast<const float4*>(&act[s4.y << 2]);
            const float4 a2 = *reinterpret_cast<const float4*>(&act[s4.z << 2]);
            const float4 a3 = *reinterpret_cast<const float4*>(&act[s4.w << 2]);

            float4 acc;   // component = batch sub
            acc.x = a0.x*w4.x + a1.x*w4.y + a2.x*w4.z + a3.x*w4.w;
            acc.y = a0.y*w4.x + a1.y*w4.y + a2.y*w4.z + a3.y*w4.w;
            acc.z = a0.z*w4.x + a1.z*w4.y + a2.z*w4.z + a3.z*w4.w;
            acc.w = a0.w*w4.x + a1.w*w4.y + a2.w*w4.z + a3.w*w4.w;

            // reduce over the 16-lane edge group
            #pragma unroll
            for (int m = 1; m <= 8; m <<= 1) {
                acc.x += __shfl_xor(acc.x, m);
                acc.y += __shfl_xor(acc.y, m);
                acc.z += __shfl_xor(acc.z, m);
                acc.w += __shfl_xor(acc.w, m);
            }

            // sigmoid (computed on all lanes to keep exec uniform; write on leader)
            float4 sg;
            sg.x = 1.f / (1.f + __expf(-acc.x));
            sg.y = 1.f / (1.f + __expf(-acc.y));
            sg.z = 1.f / (1.f + __expf(-acc.z));
            sg.w = 1.f / (1.f + __expf(-acc.w));
            if (esub == 0) {
                *reinterpret_cast<float4*>(&act[(nb + neuron) << 2]) = sg;
            }
        }
        __syncthreads();
        off += n << 6;  // n * DEG
        nb  += n;
    }

    // ---- write outputs: out[(bbase+j)*256 + i], one element per thread ----
    {
        const int j = tid >> 8;   // batch sub
        const int i = tid & 255;  // output neuron
        out[(bbase + j) * N_OUT + i] = act[(TOTAL_N - N_OUT + i) * BPB + j];
    }
}

extern "C" void kernel_launch(void* const* d_in, const int* in_sizes, int n_in,
                              void* d_out, int out_size, void* d_ws, size_t ws_size,
                              hipStream_t stream)
{
    const float* in  = (const float*)d_in[0];
    const float* wts = (const float*)d_in[1];
    const int*   sx  = (const int*)d_in[2];
    float*       out = (float*)d_out;

    neat_fwd<<<BATCH / BPB, THREADS, 0, stream>>>(in, wts, sx, out);
}

// Round 2
// 134.367 us; speedup vs baseline: 1.2125x; 1.2125x over previous
//
#include <hip/hip_runtime.h>
#include <math.h>

// NEAT forward, round 2: one LANE = one NEURON (no cross-lane reduction).
// 4 batch elements per block; full activation history (8960 x 4, f32) in LDS
// (143,360 B). 9 layers in one kernel, __syncthreads() between layers.
// Per lane per neuron: 16x int4 idx + 16x float4 w loads (L1/L2-resident),
// 64 ds_read_b128 gathers (4 batch values each), 256 FMAs, 1 sigmoid x4,
// one ds_write_b128 of the result. Zero shuffles -> DS pipe only carries
// gathers, VALU only carries FMAs.

#define N_IN    512
#define NLAYER  9
#define DEG     64
#define BATCH   1024
#define BPB     4
#define THREADS 1024
#define TOTAL_N 8960   // 512 + 8*1024 + 256
#define N_OUT   256

__global__ __launch_bounds__(THREADS, 4)
void neat_fwd(const float* __restrict__ in,
              const float* __restrict__ wts,
              const int*   __restrict__ sidx,
              float*       __restrict__ out)
{
    __shared__ float act[TOTAL_N * BPB];   // [neuron][batch-sub]

    const int tid   = threadIdx.x;
    const int bbase = blockIdx.x * BPB;

    // ---- stage inputs: rows bbase..bbase+3 are 2048 contiguous floats ----
    {
        const float* src = in + bbase * N_IN;
        for (int t = tid; t < BPB * N_IN; t += THREADS) {
            int j = t >> 9;          // batch sub 0..3
            int i = t & (N_IN - 1);  // input neuron 0..511
            act[i * BPB + j] = src[t];
        }
    }
    __syncthreads();

    int off = 0;      // edge-array offset
    int nb  = N_IN;   // neurons produced so far
    #pragma unroll 1
    for (int layer = 0; layer < NLAYER; ++layer) {
        const int n = (layer < NLAYER - 1) ? 1024 : 256;
        for (int neuron = tid; neuron < n; neuron += THREADS) {
            const int ebase = off + (neuron << 6);
            const int4*   sp = reinterpret_cast<const int4*>(sidx + ebase);
            const float4* wp = reinterpret_cast<const float4*>(wts + ebase);

            float4 acc = make_float4(0.f, 0.f, 0.f, 0.f);
            #pragma unroll 4
            for (int q = 0; q < DEG / 4; ++q) {
                const int4   s4 = sp[q];
                const float4 w4 = wp[q];
                const float4 a0 = *reinterpret_cast<const float4*>(&act[s4.x << 2]);
                const float4 a1 = *reinterpret_cast<const float4*>(&act[s4.y << 2]);
                const float4 a2 = *reinterpret_cast<const float4*>(&act[s4.z << 2]);
                const float4 a3 = *reinterpret_cast<const float4*>(&act[s4.w << 2]);
                acc.x += a0.x*w4.x + a1.x*w4.y + a2.x*w4.z + a3.x*w4.w;
                acc.y += a0.y*w4.x + a1.y*w4.y + a2.y*w4.z + a3.y*w4.w;
                acc.z += a0.z*w4.x + a1.z*w4.y + a2.z*w4.z + a3.z*w4.w;
                acc.w += a0.w*w4.x + a1.w*w4.y + a2.w*w4.z + a3.w*w4.w;
            }

            float4 sg;
            sg.x = 1.f / (1.f + __expf(-acc.x));
            sg.y = 1.f / (1.f + __expf(-acc.y));
            sg.z = 1.f / (1.f + __expf(-acc.z));
            sg.w = 1.f / (1.f + __expf(-acc.w));
            *reinterpret_cast<float4*>(&act[(nb + neuron) << 2]) = sg;
        }
        __syncthreads();
        off += n << 6;  // n * DEG
        nb  += n;
    }

    // ---- write outputs: out[(bbase+j)*256 + i], one element per thread ----
    {
        const int j = tid >> 8;   // batch sub
        const int i = tid & 255;  // output neuron
        out[(bbase + j) * N_OUT + i] = act[(TOTAL_N - N_OUT + i) * BPB + j];
    }
}

extern "C" void kernel_launch(void* const* d_in, const int* in_sizes, int n_in,
                              void* d_out, int out_size, void* d_ws, size_t ws_size,
                              hipStream_t stream)
{
    const float* in  = (const float*)d_in[0];
    const float* wts = (const float*)d_in[1];
    const int*   sx  = (const int*)d_in[2];
    float*       out = (float*)d_out;

    neat_fwd<<<BATCH / BPB, THREADS, 0, stream>>>(in, wts, sx, out);
}

// Round 3
// 58.777 us; speedup vs baseline: 2.7719x; 2.2860x over previous
//
#include <hip/hip_runtime.h>
#include <math.h>

// NEAT forward, round 3.
//  - prep kernel transposes idx+weights into d_ws as 16-B records
//    {ushort4 src_idx, bf16x4 w} laid out [layer][neuron_blk64][q][lane]
//    so the main loop's record load is one fully-coalesced dwordx4/wave.
//  - activations stored bf16 in LDS (8960 neurons x 4 batches x 2B = 71,680B)
//    -> gathers are ds_read_b64 (half the DS cycles, conflicts spread over
//    16 bank-pair groups instead of 8).
//  - accumulate f32; last layer writes f32 straight to global (no bf16
//    quantization of the output itself).

#define N_IN    512
#define NLAYER  9
#define DEG     64
#define BATCH   1024
#define BPB     4
#define THREADS 1024
#define TOTAL_N 8960    // 512 + 8*1024 + 256
#define N_OUT   256
#define NREC    135168  // E_TOTAL/4 = 540672/4

__device__ __forceinline__ unsigned f2bf(float f) {
    unsigned u = __float_as_uint(f);
    return (u + 0x7fffu + ((u >> 16) & 1u)) >> 16;   // RNE
}
__device__ __forceinline__ float bflo(unsigned u) { return __uint_as_float(u << 16); }
__device__ __forceinline__ float bfhi(unsigned u) { return __uint_as_float(u & 0xffff0000u); }

// ---- transpose idx/weights into wave-coalesced 16-B records ----
__global__ __launch_bounds__(256)
void neat_prep(const float* __restrict__ wts,
               const int*   __restrict__ sidx,
               uint4*       __restrict__ rec)
{
    int r = blockIdx.x * 256 + threadIdx.x;
    if (r >= NREC) return;
    int l = r >> 14;          // 16384 records per 1024-neuron layer; l=8 = last
    int j = r & 16383;
    int n = ((j >> 10) << 6) | (j & 63);
    int q = (j >> 6) & 15;
    int e0 = (l << 16) + (n << 6) + (q << 2);
    int4   s4 = *reinterpret_cast<const int4*>(sidx + e0);
    float4 w4 = *reinterpret_cast<const float4*>(wts + e0);
    uint4 o;
    o.x = (unsigned)s4.x | ((unsigned)s4.y << 16);
    o.y = (unsigned)s4.z | ((unsigned)s4.w << 16);
    o.z = f2bf(w4.x) | (f2bf(w4.y) << 16);
    o.w = f2bf(w4.z) | (f2bf(w4.w) << 16);
    rec[r] = o;
}

__global__ __launch_bounds__(THREADS, 4)
void neat_fwd(const float* __restrict__ in,
              const uint4* __restrict__ rec,
              float*       __restrict__ out)
{
    __shared__ unsigned short act[TOTAL_N * BPB];   // [neuron][batch], bf16

    const int tid   = threadIdx.x;
    const int bbase = blockIdx.x * BPB;

    // ---- stage inputs (f32 -> bf16) ----
    {
        const float* src = in + bbase * N_IN;
        for (int t = tid; t < BPB * N_IN; t += THREADS) {
            int j = t >> 9;           // batch sub
            int i = t & (N_IN - 1);   // input neuron
            act[i * BPB + j] = (unsigned short)f2bf(src[t]);
        }
    }
    __syncthreads();

    int recBase = 0;
    int nb      = N_IN;
    #pragma unroll 1
    for (int layer = 0; layer < NLAYER; ++layer) {
        const int n = (layer < NLAYER - 1) ? 1024 : N_OUT;
        for (int neuron = tid; neuron < n; neuron += THREADS) {
            const uint4* rp = rec + recBase + ((neuron >> 6) << 10) + (neuron & 63);

            float4 acc = make_float4(0.f, 0.f, 0.f, 0.f);
            #pragma unroll 4
            for (int q = 0; q < DEG / 4; ++q) {
                const uint4 r4 = rp[q << 6];
                const uint2 g0 = *reinterpret_cast<const uint2*>(act + ((r4.x & 0xffffu) << 2));
                const uint2 g1 = *reinterpret_cast<const uint2*>(act + ((r4.x >> 16) << 2));
                const uint2 g2 = *reinterpret_cast<const uint2*>(act + ((r4.y & 0xffffu) << 2));
                const uint2 g3 = *reinterpret_cast<const uint2*>(act + ((r4.y >> 16) << 2));
                const float w0 = bflo(r4.z), w1 = bfhi(r4.z);
                const float w2 = bflo(r4.w), w3 = bfhi(r4.w);
                acc.x += bflo(g0.x)*w0 + bflo(g1.x)*w1 + bflo(g2.x)*w2 + bflo(g3.x)*w3;
                acc.y += bfhi(g0.x)*w0 + bfhi(g1.x)*w1 + bfhi(g2.x)*w2 + bfhi(g3.x)*w3;
                acc.z += bflo(g0.y)*w0 + bflo(g1.y)*w1 + bflo(g2.y)*w2 + bflo(g3.y)*w3;
                acc.w += bfhi(g0.y)*w0 + bfhi(g1.y)*w1 + bfhi(g2.y)*w2 + bfhi(g3.y)*w3;
            }

            float4 sg;
            sg.x = 1.f / (1.f + __expf(-acc.x));
            sg.y = 1.f / (1.f + __expf(-acc.y));
            sg.z = 1.f / (1.f + __expf(-acc.z));
            sg.w = 1.f / (1.f + __expf(-acc.w));

            if (layer < NLAYER - 1) {
                uint2 p;
                p.x = f2bf(sg.x) | (f2bf(sg.y) << 16);
                p.y = f2bf(sg.z) | (f2bf(sg.w) << 16);
                *reinterpret_cast<uint2*>(act + ((nb + neuron) << 2)) = p;
            } else {
                float* op = out + neuron;          // f32 output, never quantized
                op[(bbase + 0) * N_OUT] = sg.x;
                op[(bbase + 1) * N_OUT] = sg.y;
                op[(bbase + 2) * N_OUT] = sg.z;
                op[(bbase + 3) * N_OUT] = sg.w;
            }
        }
        __syncthreads();
        recBase += n << 4;   // n * DEG / 4 records
        nb      += n;
    }
}

extern "C" void kernel_launch(void* const* d_in, const int* in_sizes, int n_in,
                              void* d_out, int out_size, void* d_ws, size_t ws_size,
                              hipStream_t stream)
{
    const float* in  = (const float*)d_in[0];
    const float* wts = (const float*)d_in[1];
    const int*   sx  = (const int*)d_in[2];
    float*       out = (float*)d_out;
    uint4*       rec = (uint4*)d_ws;    // needs 135168*16 = 2,162,688 B

    neat_prep<<<(NREC + 255) / 256, 256, 0, stream>>>(wts, sx, rec);
    neat_fwd<<<BATCH / BPB, THREADS, 0, stream>>>(in, rec, out);
}